// Round 1
// baseline (104.113 us; speedup 1.0000x reference)
//
#include <hip/hip_runtime.h>
#include <math.h>

#define N_SAMPLES 131072
#define HIDDEN 1024
#define EVAL_THREADS 256
#define EVAL_BLOCKS (N_SAMPLES / EVAL_THREADS)   // 512

__device__ __forceinline__ float softplusf(float v) {
    return fmaxf(v, 0.0f) + log1pf(expf(-fabsf(v)));
}
__device__ __forceinline__ float kl_term_f(float mu, float sigma, float inv_prior) {
    float r = sigma * inv_prior;
    float m = mu * inv_prior;
    return 0.5f * (-2.0f * logf(r) - 1.0f + r * r + m * m);
}

struct f4 { float x, y, z, w; };
__device__ __forceinline__ f4 f4add(f4 a, f4 b) { return {a.x+b.x, a.y+b.y, a.z+b.z, a.w+b.w}; }
__device__ __forceinline__ f4 f4sub(f4 a, f4 b) { return {a.x-b.x, a.y-b.y, a.z-b.z, a.w-b.w}; }

// ---------------------------------------------------------------------------
// Kernel 1: sample weights, KL (unchanged math), then build the piecewise-
// linear representation: out(x) = C[k].A * x + C[k].I  where
// k = #{ thresholds t_j < x },  t_j = -b1_j / w1_j.
//   unit j (w1>0): active for x > t_j   -> + in prefix direction
//   unit j (w1<0): active for x < t_j   -> counted via T_neg - prefix
// C(k) = exclusive_prefix(signed v)(k) + T_neg  (+ b2 folded into intercepts)
// One block, 1024 threads: sample -> bitonic sort (key,idx) -> gather ->
// block scan -> table to workspace.
// ---------------------------------------------------------------------------
__global__ __launch_bounds__(1024) void bbb_prep(
    const float* __restrict__ W1_mu, const float* __restrict__ W1_rho,
    const float* __restrict__ b1_mu, const float* __restrict__ b1_rho,
    const float* __restrict__ W2_mu, const float* __restrict__ W2_rho,
    const float* __restrict__ b2_mu, const float* __restrict__ b2_rho,
    const float* __restrict__ eps_W1, const float* __restrict__ eps_b1,
    const float* __restrict__ eps_W2, const float* __restrict__ eps_b2,
    float* __restrict__ t_out,      // [HIDDEN]   sorted thresholds
    float4* __restrict__ C_out,     // [HIDDEN+1] segment coefficients
    float* __restrict__ kl_out)     // scalar
{
    __shared__ float  s_key[HIDDEN];
    __shared__ int    s_idx[HIDDEN];
    __shared__ f4     s_v[HIDDEN];
    __shared__ double s_part[16];
    __shared__ f4     s_wtot[16];
    __shared__ f4     s_negtot[16];
    __shared__ float  s_b2[2];

    const int tid  = threadIdx.x;
    const int lane = tid & 63;
    const int wid  = tid >> 6;

    const float ip1 = 0.25f;          // 1 / (4.0/sqrt(1))
    const float ip2 = 32.0f / 2.25f;  // 1 / (2.25/sqrt(1024))

    float w1mu  = W1_mu[tid],          w1rho  = W1_rho[tid];
    float b1mu  = b1_mu[tid],          b1rho  = b1_rho[tid];
    float w2amu = W2_mu[tid],          w2arho = W2_rho[tid];
    float w2bmu = W2_mu[HIDDEN + tid], w2brho = W2_rho[HIDDEN + tid];

    float sg_w1  = softplusf(w1rho);
    float sg_b1  = softplusf(b1rho);
    float sg_w2a = softplusf(w2arho);
    float sg_w2b = softplusf(w2brho);

    float w1  = fmaf(sg_w1,  eps_W1[tid],          w1mu);
    float bb1 = fmaf(sg_b1,  eps_b1[tid],          b1mu);
    float w2a = fmaf(sg_w2a, eps_W2[tid],          w2amu);
    float w2b = fmaf(sg_w2b, eps_W2[HIDDEN + tid], w2bmu);

    if (tid == 0) {
        s_b2[0] = fmaf(softplusf(b2_rho[0]), eps_b2[0], b2_mu[0]);
        s_b2[1] = fmaf(softplusf(b2_rho[1]), eps_b2[1], b2_mu[1]);
    }

    // hinge: contribution when active is (w2*w1)*x + (w2*bb1)
    float sa = w2a * w1, ia = w2a * bb1;
    float sb = w2b * w1, ib = w2b * bb1;
    bool  pos = (w1 > 0.0f);
    float t = -bb1 / w1;
    if (w1 == 0.0f) {   // degenerate: constant relu(bb1) contribution
        pos = true;
        t = (bb1 > 0.0f) ? -INFINITY : INFINITY;
    }

    f4 raw  = {sa, ia, sb, ib};
    f4 v    = pos ? raw : f4{-sa, -ia, -sb, -ib};
    f4 vneg = pos ? f4{0.0f, 0.0f, 0.0f, 0.0f} : raw;

    s_key[tid] = t;
    s_idx[tid] = tid;
    s_v[tid]   = v;

    // ---- KL (identical to previous verified version) ----
    double kl = (double)kl_term_f(w1mu,  sg_w1,  ip1)
              + (double)kl_term_f(b1mu,  sg_b1,  ip1)
              + (double)kl_term_f(w2amu, sg_w2a, ip2)
              + (double)kl_term_f(w2bmu, sg_w2b, ip2);
    if (tid < 2) kl += (double)kl_term_f(b2_mu[tid], softplusf(b2_rho[tid]), ip2);
    #pragma unroll
    for (int off = 32; off > 0; off >>= 1) kl += __shfl_down(kl, off, 64);
    if (lane == 0) s_part[wid] = kl;

    // ---- per-wave reduce of negative-class raw totals ----
    #pragma unroll
    for (int off = 32; off > 0; off >>= 1) {
        vneg.x += __shfl_down(vneg.x, off, 64);
        vneg.y += __shfl_down(vneg.y, off, 64);
        vneg.z += __shfl_down(vneg.z, off, 64);
        vneg.w += __shfl_down(vneg.w, off, 64);
    }
    if (lane == 0) s_negtot[wid] = vneg;

    __syncthreads();

    if (tid == 0) {
        double tt = 0.0;
        #pragma unroll
        for (int i = 0; i < 16; ++i) tt += s_part[i];
        *kl_out = (float)tt;
    }

    // ---- bitonic sort of (key, idx), ascending ----
    for (int k = 2; k <= HIDDEN; k <<= 1) {
        for (int j = k >> 1; j > 0; j >>= 1) {
            int ixj = tid ^ j;
            if (ixj > tid) {
                float a = s_key[tid], b = s_key[ixj];
                bool up = ((tid & k) == 0);
                if ((a > b) == up) {
                    s_key[tid] = b; s_key[ixj] = a;
                    int ti = s_idx[tid]; s_idx[tid] = s_idx[ixj]; s_idx[ixj] = ti;
                }
            }
            __syncthreads();
        }
    }

    float tkey = s_key[tid];
    f4 vs = s_v[s_idx[tid]];   // signed payload in sorted order

    // total over negative-class units
    f4 tneg = s_negtot[0];
    #pragma unroll
    for (int i = 1; i < 16; ++i) tneg = f4add(tneg, s_negtot[i]);

    // ---- block-wide inclusive scan of vs (wave scan + wave offsets) ----
    f4 incl = vs;
    #pragma unroll
    for (int off = 1; off < 64; off <<= 1) {
        float ax = __shfl_up(incl.x, off, 64);
        float ay = __shfl_up(incl.y, off, 64);
        float az = __shfl_up(incl.z, off, 64);
        float aw = __shfl_up(incl.w, off, 64);
        if (lane >= off) { incl.x += ax; incl.y += ay; incl.z += az; incl.w += aw; }
    }
    if (lane == 63) s_wtot[wid] = incl;
    __syncthreads();

    f4 offs = {0.0f, 0.0f, 0.0f, 0.0f};
    #pragma unroll
    for (int w = 0; w < 16; ++w) {
        if (w < wid) offs = f4add(offs, s_wtot[w]);
    }

    f4 excl = f4sub(f4add(offs, incl), vs);   // exclusive prefix at rank tid
    f4 C = f4add(excl, tneg);
    C.y += s_b2[0];   // fold sampled b2 into intercepts
    C.w += s_b2[1];

    t_out[tid] = tkey;
    C_out[tid] = make_float4(C.x, C.y, C.z, C.w);
    if (tid == HIDDEN - 1) {
        f4 Cl = f4add(f4add(offs, incl), tneg);   // k = HIDDEN segment
        Cl.y += s_b2[0];
        Cl.w += s_b2[1];
        C_out[HIDDEN] = make_float4(Cl.x, Cl.y, Cl.z, Cl.w);
    }
}

// ---------------------------------------------------------------------------
// Kernel 2: per sample -> binary search the 1024 sorted thresholds in LDS
// (11 dependent ds_read_b32), fetch float4 coeffs, 2 FMA + softplus. Replaces
// the 1024-unit dense loop entirely.
// ---------------------------------------------------------------------------
__global__ __launch_bounds__(EVAL_THREADS) void bbb_eval(
    const float* __restrict__ x,
    const float* __restrict__ t_sorted,
    const float4* __restrict__ Ctab,
    float* __restrict__ means,
    float* __restrict__ stds)
{
    __shared__ float  s_t[HIDDEN];
    __shared__ float4 s_C[HIDDEN + 1];

    const int tid = threadIdx.x;
    for (int i = tid; i < HIDDEN; i += EVAL_THREADS) s_t[i] = t_sorted[i];
    for (int i = tid; i < HIDDEN + 1; i += EVAL_THREADS) s_C[i] = Ctab[i];
    __syncthreads();

    const int g = blockIdx.x * EVAL_THREADS + tid;
    const float xv = x[g];

    // branchless lower_bound: k = #{ t < xv }, k in [0, 1024]
    int base = 0;
    #pragma unroll
    for (int half = 512; half > 0; half >>= 1) {
        if (s_t[base + half - 1] < xv) base += half;
    }
    int k = base + ((s_t[base] < xv) ? 1 : 0);

    float4 c = s_C[k];
    means[g] = fmaf(c.x, xv, c.y);
    stds[g]  = 1e-5f + softplusf(fmaf(c.z, xv, c.w));
}

extern "C" void kernel_launch(void* const* d_in, const int* in_sizes, int n_in,
                              void* d_out, int out_size, void* d_ws, size_t ws_size,
                              hipStream_t stream) {
    const float* x      = (const float*)d_in[0];
    const float* W1_mu  = (const float*)d_in[1];
    const float* W1_rho = (const float*)d_in[2];
    const float* b1_mu  = (const float*)d_in[3];
    const float* b1_rho = (const float*)d_in[4];
    const float* W2_mu  = (const float*)d_in[5];
    const float* W2_rho = (const float*)d_in[6];
    const float* b2_mu  = (const float*)d_in[7];
    const float* b2_rho = (const float*)d_in[8];
    const float* eps_W1 = (const float*)d_in[9];
    const float* eps_b1 = (const float*)d_in[10];
    const float* eps_W2 = (const float*)d_in[11];
    const float* eps_b2 = (const float*)d_in[12];

    float* out = (float*)d_out;
    float*  t_ws = (float*)d_ws;                        // 4 KB sorted thresholds
    float4* C_ws = (float4*)((char*)d_ws + 4096);       // 16.4 KB coefficient table

    bbb_prep<<<1, HIDDEN, 0, stream>>>(
        W1_mu, W1_rho, b1_mu, b1_rho, W2_mu, W2_rho, b2_mu, b2_rho,
        eps_W1, eps_b1, eps_W2, eps_b2,
        t_ws, C_ws, out + 2 * N_SAMPLES);

    bbb_eval<<<EVAL_BLOCKS, EVAL_THREADS, 0, stream>>>(
        x, t_ws, C_ws, out, out + N_SAMPLES);
}

// Round 2
// 96.664 us; speedup vs baseline: 1.0771x; 1.0771x over previous
//
#include <hip/hip_runtime.h>
#include <math.h>

#define N_SAMPLES 131072
#define HIDDEN 1024
#define SEGS 8
#define SEG_UNITS (HIDDEN / SEGS)        // 128
#define PAIRS 128                        // sample-pairs per block
#define SAMPLES_PER_BLOCK (2 * PAIRS)    // 256
#define BLOCKS (N_SAMPLES / SAMPLES_PER_BLOCK)  // 512

typedef float v2f __attribute__((ext_vector_type(2)));

__device__ __forceinline__ float softplusf(float v) {
    return fmaxf(v, 0.0f) + log1pf(expf(-fabsf(v)));
}
__device__ __forceinline__ float kl_term_f(float mu, float sigma, float inv_prior) {
    float r = sigma * inv_prior;
    float m = mu * inv_prior;
    return 0.5f * (-2.0f * logf(r) - 1.0f + r * r + m * m);
}

// ---------------------------------------------------------------------------
// Fused kernel: every block re-samples the weights (redundant, cheap: 24 KB
// coalesced L2-resident reads + 4 softplus per thread), stages the per-unit
// {w1, b1, w2a, w2b} table in LDS, then runs the verified split-8 dense eval
// (2 samples/thread, packed f32). KL is reduced and written by block 0 only.
// One launch, no workspace, no serial 1-block prep on the critical path.
// ---------------------------------------------------------------------------
__global__ __launch_bounds__(1024) void bbb_fused(
    const float* __restrict__ x,
    const float* __restrict__ W1_mu, const float* __restrict__ W1_rho,
    const float* __restrict__ b1_mu, const float* __restrict__ b1_rho,
    const float* __restrict__ W2_mu, const float* __restrict__ W2_rho,
    const float* __restrict__ b2_mu, const float* __restrict__ b2_rho,
    const float* __restrict__ eps_W1, const float* __restrict__ eps_b1,
    const float* __restrict__ eps_W2, const float* __restrict__ eps_b2,
    float* __restrict__ means,
    float* __restrict__ stds,
    float* __restrict__ kl_out)
{
    __shared__ float4 s_params[HIDDEN];       // 16 KB   {w1, b1, w2a, w2b}
    __shared__ float4 s_part[SEGS][PAIRS];    // 16 KB   partial sums
    __shared__ double s_kl[16];
    __shared__ float  s_b2[2];

    const int tid  = threadIdx.x;
    const int lane = tid & 63;
    const int wid  = tid >> 6;

    const float ip1 = 0.25f;          // 1 / (4.0/sqrt(1))
    const float ip2 = 32.0f / 2.25f;  // 1 / (2.25/sqrt(1024))

    // ---- sampling (all blocks; coalesced, L2-resident) ----
    float w1mu  = W1_mu[tid],          w1rho  = W1_rho[tid];
    float b1mu  = b1_mu[tid],          b1rho  = b1_rho[tid];
    float w2amu = W2_mu[tid],          w2arho = W2_rho[tid];
    float w2bmu = W2_mu[HIDDEN + tid], w2brho = W2_rho[HIDDEN + tid];

    float sg_w1  = softplusf(w1rho);
    float sg_b1  = softplusf(b1rho);
    float sg_w2a = softplusf(w2arho);
    float sg_w2b = softplusf(w2brho);

    float w1  = fmaf(sg_w1,  eps_W1[tid],          w1mu);
    float bb1 = fmaf(sg_b1,  eps_b1[tid],          b1mu);
    float w2a = fmaf(sg_w2a, eps_W2[tid],          w2amu);
    float w2b = fmaf(sg_w2b, eps_W2[HIDDEN + tid], w2bmu);

    s_params[tid] = make_float4(w1, bb1, w2a, w2b);

    if (tid == 0) {
        s_b2[0] = fmaf(softplusf(b2_rho[0]), eps_b2[0], b2_mu[0]);
        s_b2[1] = fmaf(softplusf(b2_rho[1]), eps_b2[1], b2_mu[1]);
    }

    // ---- KL: block 0 only (identical math to verified baseline) ----
    if (blockIdx.x == 0) {
        double kl = (double)kl_term_f(w1mu,  sg_w1,  ip1)
                  + (double)kl_term_f(b1mu,  sg_b1,  ip1)
                  + (double)kl_term_f(w2amu, sg_w2a, ip2)
                  + (double)kl_term_f(w2bmu, sg_w2b, ip2);
        if (tid < 2) kl += (double)kl_term_f(b2_mu[tid], softplusf(b2_rho[tid]), ip2);
        #pragma unroll
        for (int off = 32; off > 0; off >>= 1) kl += __shfl_down(kl, off, 64);
        if (lane == 0) s_kl[wid] = kl;
    }

    __syncthreads();

    if (blockIdx.x == 0 && tid == 0) {
        double t = 0.0;
        #pragma unroll
        for (int i = 0; i < 16; ++i) t += s_kl[i];
        *kl_out = (float)t;
    }

    // ---- dense eval: split-8 over units, 2 samples/thread, packed f32 ----
    const int pair = tid & (PAIRS - 1);
    const int seg  = __builtin_amdgcn_readfirstlane(tid >> 7);  // wave-uniform
    const int base = blockIdx.x * SAMPLES_PER_BLOCK;

    const v2f xv = *(const v2f*)(x + base + 2 * pair);

    const float4* p = &s_params[seg * SEG_UNITS];

    v2f aa = {0.0f, 0.0f};
    v2f ab = {0.0f, 0.0f};
    #pragma unroll 8
    for (int j = 0; j < SEG_UNITS; ++j) {
        float4 q = p[j];                     // wave-uniform -> LDS broadcast
        v2f h = __builtin_elementwise_fma((v2f)q.x, xv, (v2f)q.y);
        h = __builtin_elementwise_max(h, (v2f)0.0f);
        aa = __builtin_elementwise_fma(h, (v2f)q.z, aa);
        ab = __builtin_elementwise_fma(h, (v2f)q.w, ab);
    }
    s_part[seg][pair] = make_float4(aa.x, aa.y, ab.x, ab.y);
    __syncthreads();

    if (tid < PAIRS) {
        float4 acc = s_part[0][tid];
        #pragma unroll
        for (int s = 1; s < SEGS; ++s) {
            float4 v = s_part[s][tid];
            acc.x += v.x; acc.y += v.y; acc.z += v.z; acc.w += v.w;
        }
        float b2a = s_b2[0], b2b = s_b2[1];
        float m0 = acc.x + b2a;
        float m1 = acc.y + b2a;
        float u0 = acc.z + b2b;
        float u1 = acc.w + b2b;
        *(float2*)(means + base + 2 * tid) = make_float2(m0, m1);
        *(float2*)(stds  + base + 2 * tid) =
            make_float2(1e-5f + softplusf(u0), 1e-5f + softplusf(u1));
    }
}

extern "C" void kernel_launch(void* const* d_in, const int* in_sizes, int n_in,
                              void* d_out, int out_size, void* d_ws, size_t ws_size,
                              hipStream_t stream) {
    const float* x      = (const float*)d_in[0];
    const float* W1_mu  = (const float*)d_in[1];
    const float* W1_rho = (const float*)d_in[2];
    const float* b1_mu  = (const float*)d_in[3];
    const float* b1_rho = (const float*)d_in[4];
    const float* W2_mu  = (const float*)d_in[5];
    const float* W2_rho = (const float*)d_in[6];
    const float* b2_mu  = (const float*)d_in[7];
    const float* b2_rho = (const float*)d_in[8];
    const float* eps_W1 = (const float*)d_in[9];
    const float* eps_b1 = (const float*)d_in[10];
    const float* eps_W2 = (const float*)d_in[11];
    const float* eps_b2 = (const float*)d_in[12];

    float* out = (float*)d_out;

    bbb_fused<<<BLOCKS, 1024, 0, stream>>>(
        x,
        W1_mu, W1_rho, b1_mu, b1_rho, W2_mu, W2_rho, b2_mu, b2_rho,
        eps_W1, eps_b1, eps_W2, eps_b2,
        out, out + N_SAMPLES, out + 2 * N_SAMPLES);
}